// Round 1
// baseline (241.306 us; speedup 1.0000x reference)
//
#include <hip/hip_runtime.h>

#define NUSERS  6041
#define NMOVIES 3953
#define EMB     32
#define NGEN    18
#define H1N     64
#define H2N     32
#define H3N     16

typedef __bf16 bf16_t;
typedef bf16_t bf16x8 __attribute__((ext_vector_type(8)));
typedef bf16_t bf16x4 __attribute__((ext_vector_type(4)));
typedef float  f32x4  __attribute__((ext_vector_type(4)));
typedef float  f32x8  __attribute__((ext_vector_type(8)));

__device__ __forceinline__ f32x4 mfma16(bf16x8 a, bf16x8 b, f32x4 c) {
    return __builtin_amdgcn_mfma_f32_16x16x32_bf16(a, b, c, 0, 0, 0);
}
__device__ __forceinline__ bf16x8 cvt8(f32x8 v) {
    bf16x8 o;
    #pragma unroll
    for (int i = 0; i < 8; ++i) o[i] = (bf16_t)v[i];
    return o;
}

#define L1STRIDE 68   // h1 transpose buffer stride (floats)
#define L2STRIDE 36   // h2 transpose buffer stride
#define RSTRIDE  28   // (fallback kernel only)
#define RBUFSZ   (16 * RSTRIDE)

// rest row layout (bf16, 24 elems = 48 B, matches W1 rest k-order):
//   [0]=gender [1]=age [2]=occupation [3..20]=genres[0..17] [21..23]=0
#define RESTW 24

#define TAB_U4   (NUSERS * EMB / 4)            // 48328 float4 chunks
#define TAB_M4   (NMOVIES * EMB / 4)           // 31624
#define TAB4TOT  (TAB_U4 + TAB_M4)             // 79952

// ---------------------------------------------------------------------------
// prep: pack rest features to bf16 rows + convert embedding tables to bf16
// ---------------------------------------------------------------------------
__global__ __launch_bounds__(256)
void prep_all(const float* __restrict__ gender,
              const float* __restrict__ age,
              const float* __restrict__ occupation,
              const float* __restrict__ genres,
              const float* __restrict__ user_table,
              const float* __restrict__ movie_table,
              bf16_t* __restrict__ rest,
              bf16_t* __restrict__ utab,
              bf16_t* __restrict__ mtab,
              int n)
{
    const int t = blockIdx.x * blockDim.x + threadIdx.x;

    // --- embedding tables -> bf16 (first ~80K threads) ---
    if (t < TAB4TOT) {
        if (t < TAB_U4) {
            float4 v = *(const float4*)(user_table + (size_t)t * 4);
            bf16x4 o; o[0]=(bf16_t)v.x; o[1]=(bf16_t)v.y; o[2]=(bf16_t)v.z; o[3]=(bf16_t)v.w;
            *(bf16x4*)(utab + (size_t)t * 4) = o;
        } else {
            const int u = t - TAB_U4;
            float4 v = *(const float4*)(movie_table + (size_t)u * 4);
            bf16x4 o; o[0]=(bf16_t)v.x; o[1]=(bf16_t)v.y; o[2]=(bf16_t)v.z; o[3]=(bf16_t)v.w;
            *(bf16x4*)(mtab + (size_t)u * 4) = o;
        }
    }

    // --- rest row pack: one thread per row ---
    if (t < n) {
        const float* gr = genres + (size_t)t * NGEN;
        float x[NGEN];
        #pragma unroll
        for (int j = 0; j < 9; ++j) {           // row byte base = t*72, 8B-aligned
            float2 v = *(const float2*)(gr + 2 * j);
            x[2 * j] = v.x; x[2 * j + 1] = v.y;
        }
        const float gg = gender[t], aa = age[t], oo = occupation[t];

        bf16x8 c0, c1, c2;
        c0[0]=(bf16_t)gg;  c0[1]=(bf16_t)aa;  c0[2]=(bf16_t)oo;
        c0[3]=(bf16_t)x[0]; c0[4]=(bf16_t)x[1]; c0[5]=(bf16_t)x[2];
        c0[6]=(bf16_t)x[3]; c0[7]=(bf16_t)x[4];
        #pragma unroll
        for (int j = 0; j < 8; ++j) c1[j] = (bf16_t)x[5 + j];
        #pragma unroll
        for (int j = 0; j < 5; ++j) c2[j] = (bf16_t)x[13 + j];
        c2[5] = (bf16_t)0.0f; c2[6] = (bf16_t)0.0f; c2[7] = (bf16_t)0.0f;

        bf16_t* op = rest + (size_t)t * RESTW;
        *(bf16x8*)(op)      = c0;
        *(bf16x8*)(op + 8)  = c1;
        *(bf16x8*)(op + 16) = c2;
    }
}

// ---------------------------------------------------------------------------
// main: lean MFMA loop, all A-fragments are direct 16 B bf16 loads
// ---------------------------------------------------------------------------
__global__ __launch_bounds__(256)
void wd_fwd_main(const int*   __restrict__ user_ids,
                 const int*   __restrict__ movie_ids,
                 const float* __restrict__ wide_W,
                 const float* __restrict__ wide_b,
                 const float* __restrict__ W1,
                 const float* __restrict__ b1,
                 const float* __restrict__ W2,
                 const float* __restrict__ b2,
                 const float* __restrict__ W3,
                 const float* __restrict__ b3,
                 const float* __restrict__ W4,
                 const float* __restrict__ b4,
                 const bf16_t* __restrict__ utab,
                 const bf16_t* __restrict__ mtab,
                 const bf16_t* __restrict__ rest,
                 float*       __restrict__ out,
                 int n)
{
    const int lane = threadIdx.x & 63;
    const int wib  = threadIdx.x >> 6;
    const int m    = lane & 15;
    const int quad = lane >> 4;

    __shared__ float lds1[4][16 * L1STRIDE];        // 17408 B
    __shared__ float lds2[4][16 * L2STRIDE];        //  9216 B
    float* __restrict__ L1p = lds1[wib];
    float* __restrict__ L2p = lds2[wib];

    // ---------------- weight-fragment preload (loop-invariant) ----------------
    bf16x8 B1f[3][4];
    #pragma unroll
    for (int kt = 0; kt < 3; ++kt)
        #pragma unroll
        for (int nt = 0; nt < 4; ++nt) {
            bf16x8 f;
            #pragma unroll
            for (int j = 0; j < 8; ++j) {
                const int k  = kt * 32 + quad * 8 + j;
                const float v = (k < 85) ? W1[k * H1N + nt * 16 + m] : 0.0f;
                f[j] = (bf16_t)v;
            }
            B1f[kt][nt] = f;
        }
    bf16x8 Bwf;
    {
        const float* wr = wide_W + NUSERS + NMOVIES;
        #pragma unroll
        for (int j = 0; j < 8; ++j) {
            const int k = 64 + quad * 8 + j;
            float v = 0.0f;
            if (m == 0) { if (k < 85) v = wr[k - 64]; else if (k == 85) v = 1.0f; }
            Bwf[j] = (bf16_t)v;
        }
    }
    bf16x8 B2f[2][2];
    #pragma unroll
    for (int kt = 0; kt < 2; ++kt)
        #pragma unroll
        for (int nt = 0; nt < 2; ++nt) {
            bf16x8 f;
            #pragma unroll
            for (int j = 0; j < 8; ++j)
                f[j] = (bf16_t)W2[(kt * 32 + quad * 8 + j) * H2N + nt * 16 + m];
            B2f[kt][nt] = f;
        }
    bf16x8 B3f;
    #pragma unroll
    for (int j = 0; j < 8; ++j) B3f[j] = (bf16_t)W3[(quad * 8 + j) * H3N + m];

    float bias1[4], bias2[2];
    #pragma unroll
    for (int nt = 0; nt < 4; ++nt) bias1[nt] = b1[nt * 16 + m];
    #pragma unroll
    for (int nt = 0; nt < 2; ++nt) bias2[nt] = b2[nt * 16 + m];
    const float bias3 = b3[m];
    const float w4v   = W4[m];
    const float b4v   = b4[0];
    const float wb0   = wide_b[0];

    const int ntiles = (n + 15) >> 4;
    const int gwave  = blockIdx.x * 4 + wib;
    const int nwaves = gridDim.x * 4;
    int niter = 0;
    if (gwave < ntiles) niter = (ntiles - gwave + nwaves - 1) / nwaves;
    if (niter == 0) return;   // no barriers anywhere in this kernel

    int t_c = gwave;
    int t_n = t_c + nwaves; if (t_n >= ntiles) t_n = t_c;

    // prologue: tile t_c's ids / rest / wide scalars
    int rc = t_c * 16 + m; if (rc >= n) rc = n - 1;
    int uid_c = user_ids[rc], mid_c = movie_ids[rc];
    bf16x8 A2c;
    #pragma unroll
    for (int j = 0; j < 8; ++j) A2c[j] = (bf16_t)0.0f;
    if (quad < 3) A2c = *(const bf16x8*)(rest + (size_t)rc * RESTW + quad * 8);
    float wuc = 0.0f, wmc = 0.0f;
    if (quad == 2) { wuc = wide_W[uid_c]; wmc = wide_W[NUSERS + mid_c]; }

    for (int i = 0; i < niter; ++i) {
        // ---- 1. current-tile embedding gathers (uids ready since last iter) ----
        const bf16x8 A0 = *(const bf16x8*)(utab + (size_t)uid_c * EMB + quad * 8);
        const bf16x8 A1 = *(const bf16x8*)(mtab + (size_t)mid_c * EMB + quad * 8);

        // ---- 2. next-tile prefetch (rest stream + ids + wide scalars) ----
        const bool more = (i + 1 < niter);
        int uid_n = uid_c, mid_n = mid_c;
        bf16x8 A2n = A2c;
        float wun = wuc, wmn = wmc;
        int t_n2 = t_n;
        if (more) {
            int rn = t_n * 16 + m; if (rn >= n) rn = n - 1;
            uid_n = user_ids[rn]; mid_n = movie_ids[rn];
            #pragma unroll
            for (int j = 0; j < 8; ++j) A2n[j] = (bf16_t)0.0f;
            if (quad < 3) A2n = *(const bf16x8*)(rest + (size_t)rn * RESTW + quad * 8);
            wun = 0.0f; wmn = 0.0f;
            if (quad == 2) { wun = wide_W[uid_n]; wmn = wide_W[NUSERS + mid_n]; }
            t_n2 = t_n + nwaves; if (t_n2 >= ntiles) t_n2 = t_n;
        }

        // ---- 3. compute tile t_c ----
        const int base = t_c << 4;
        bf16x8 A2 = A2c;
        if (quad == 2) A2[5] = (bf16_t)(wuc + wmc + wb0);   // k == 85 synthetic wide feature

        f32x4 accw = mfma16(A2, Bwf, (f32x4){0.f, 0.f, 0.f, 0.f});

        f32x4 acc[4];
        #pragma unroll
        for (int nt = 0; nt < 4; ++nt) {
            f32x4 c = {bias1[nt], bias1[nt], bias1[nt], bias1[nt]};
            c = mfma16(A2, B1f[2][nt], c);   // rest chunk first: A2 ready from prefetch
            c = mfma16(A1, B1f[1][nt], c);
            c = mfma16(A0, B1f[0][nt], c);
            acc[nt] = c;
        }
        #pragma unroll
        for (int nt = 0; nt < 4; ++nt)
            #pragma unroll
            for (int r = 0; r < 4; ++r)
                L1p[(quad * 4 + r) * L1STRIDE + nt * 16 + m] = fmaxf(acc[nt][r], 0.0f);

        bf16x8 AL2[2];
        #pragma unroll
        for (int kt = 0; kt < 2; ++kt) {
            const float4* s = (const float4*)(L1p + m * L1STRIDE + kt * 32 + quad * 8);
            float4 a = s[0], b = s[1];
            f32x8 t8; t8[0]=a.x; t8[1]=a.y; t8[2]=a.z; t8[3]=a.w;
            t8[4]=b.x; t8[5]=b.y; t8[6]=b.z; t8[7]=b.w;
            AL2[kt] = cvt8(t8);
        }

        f32x4 acc2[2];
        #pragma unroll
        for (int nt = 0; nt < 2; ++nt) {
            f32x4 c = {bias2[nt], bias2[nt], bias2[nt], bias2[nt]};
            c = mfma16(AL2[0], B2f[0][nt], c);
            c = mfma16(AL2[1], B2f[1][nt], c);
            acc2[nt] = c;
        }
        #pragma unroll
        for (int nt = 0; nt < 2; ++nt)
            #pragma unroll
            for (int r = 0; r < 4; ++r)
                L2p[(quad * 4 + r) * L2STRIDE + nt * 16 + m] = fmaxf(acc2[nt][r], 0.0f);

        bf16x8 AL3;
        {
            const float4* s = (const float4*)(L2p + m * L2STRIDE + quad * 8);
            float4 a = s[0], b = s[1];
            f32x8 t8; t8[0]=a.x; t8[1]=a.y; t8[2]=a.z; t8[3]=a.w;
            t8[4]=b.x; t8[5]=b.y; t8[6]=b.z; t8[7]=b.w;
            AL3 = cvt8(t8);
        }

        f32x4 acc3 = mfma16(AL3, B3f, (f32x4){bias3, bias3, bias3, bias3});

        float t0 = fmaxf(acc3[0], 0.0f) * w4v + accw[0];
        float t1 = fmaxf(acc3[1], 0.0f) * w4v + accw[1];
        float t2 = fmaxf(acc3[2], 0.0f) * w4v + accw[2];
        float t3 = fmaxf(acc3[3], 0.0f) * w4v + accw[3];
        #pragma unroll
        for (int off = 1; off < 16; off <<= 1) {
            t0 += __shfl_xor(t0, off, 64);
            t1 += __shfl_xor(t1, off, 64);
            t2 += __shfl_xor(t2, off, 64);
            t3 += __shfl_xor(t3, off, 64);
        }
        if (m < 4) {
            float zv = t0;
            zv = (m == 1) ? t1 : zv;
            zv = (m == 2) ? t2 : zv;
            zv = (m == 3) ? t3 : zv;
            zv += b4v;
            const int orow = base + quad * 4 + m;
            if (orow < n) out[orow] = 1.0f / (1.0f + __expf(-zv));
        }

        // ---- 4. rotate pipeline ----
        if (more) {
            A2c = A2n; wuc = wun; wmc = wmn;
            uid_c = uid_n; mid_c = mid_n;
            t_c = t_n; t_n = t_n2;
        }
    }
}

// ---------------------------------------------------------------------------
// fallback: previous verified kernel (used only if workspace is too small)
// ---------------------------------------------------------------------------
struct Pref {
    float4 u0, u1, m0, m1;
    float  wu, wm;
};

__global__ __launch_bounds__(256)
void wd_fwd_pipe(const int*   __restrict__ user_ids,
                 const int*   __restrict__ movie_ids,
                 const float* __restrict__ gender,
                 const float* __restrict__ age,
                 const float* __restrict__ occupation,
                 const float* __restrict__ genres,
                 const float* __restrict__ wide_W,
                 const float* __restrict__ wide_b,
                 const float* __restrict__ user_table,
                 const float* __restrict__ movie_table,
                 const float* __restrict__ W1,
                 const float* __restrict__ b1,
                 const float* __restrict__ W2,
                 const float* __restrict__ b2,
                 const float* __restrict__ W3,
                 const float* __restrict__ b3,
                 const float* __restrict__ W4,
                 const float* __restrict__ b4,
                 float*       __restrict__ out,
                 int n)
{
    const int lane = threadIdx.x & 63;
    const int wib  = threadIdx.x >> 6;
    const int m    = lane & 15;
    const int quad = lane >> 4;

    __shared__ float lds_rest[4][2 * RBUFSZ];
    __shared__ float lds1[4][16 * L1STRIDE];
    __shared__ float lds2[4][16 * L2STRIDE];
    float* __restrict__ rbase = lds_rest[wib];
    float* __restrict__ L1p   = lds1[wib];
    float* __restrict__ L2p   = lds2[wib];

    for (int k = lane; k < 2 * RBUFSZ; k += 64) rbase[k] = 0.0f;

    bf16x8 B1f[3][4];
    #pragma unroll
    for (int kt = 0; kt < 3; ++kt)
        #pragma unroll
        for (int nt = 0; nt < 4; ++nt) {
            bf16x8 f;
            #pragma unroll
            for (int j = 0; j < 8; ++j) {
                const int k  = kt * 32 + quad * 8 + j;
                const float v = (k < 85) ? W1[k * H1N + nt * 16 + m] : 0.0f;
                f[j] = (bf16_t)v;
            }
            B1f[kt][nt] = f;
        }
    bf16x8 Bwf;
    {
        const float* wr = wide_W + NUSERS + NMOVIES;
        #pragma unroll
        for (int j = 0; j < 8; ++j) {
            const int k = 64 + quad * 8 + j;
            float v = 0.0f;
            if (m == 0) { if (k < 85) v = wr[k - 64]; else if (k == 85) v = 1.0f; }
            Bwf[j] = (bf16_t)v;
        }
    }
    bf16x8 B2f[2][2];
    #pragma unroll
    for (int kt = 0; kt < 2; ++kt)
        #pragma unroll
        for (int nt = 0; nt < 2; ++nt) {
            bf16x8 f;
            #pragma unroll
            for (int j = 0; j < 8; ++j)
                f[j] = (bf16_t)W2[(kt * 32 + quad * 8 + j) * H2N + nt * 16 + m];
            B2f[kt][nt] = f;
        }
    bf16x8 B3f;
    #pragma unroll
    for (int j = 0; j < 8; ++j) B3f[j] = (bf16_t)W3[(quad * 8 + j) * H3N + m];

    float bias1[4], bias2[2];
    #pragma unroll
    for (int nt = 0; nt < 4; ++nt) bias1[nt] = b1[nt * 16 + m];
    #pragma unroll
    for (int nt = 0; nt < 2; ++nt) bias2[nt] = b2[nt * 16 + m];
    const float bias3 = b3[m];
    const float w4v   = W4[m];
    const float b4v   = b4[0];
    const float wb0   = wide_b[0];

    const int ntiles = (n + 15) >> 4;
    const int gwave  = blockIdx.x * 4 + wib;
    const int nwaves = gridDim.x * 4;
    int niter = 0;
    if (gwave < ntiles) niter = (ntiles - gwave + nwaves - 1) / nwaves;
    const long gmax = (long)n * NGEN - 1;

#define LOAD_IDS(tt, U, M) { int rr = (tt) * 16 + m; rr = rr < n ? rr : n - 1; \
                             U = user_ids[rr]; M = movie_ids[rr]; }
#define LOAD_GENRES(tt, G, SC) { \
    const long gb = (long)(tt) * (16 * NGEN); \
    _Pragma("unroll") \
    for (int r = 0; r < 4; ++r) { long idx = gb + lane + r * 64; \
        idx = idx < gmax ? idx : gmax; G[r] = genres[idx]; } \
    { long idx = gb + lane + 256; idx = idx < gmax ? idx : gmax; \
      G[4] = (lane < 32) ? genres[idx] : 0.0f; } \
    { int rr = (tt) * 16 + m; rr = rr < n ? rr : n - 1; \
      const float* sp = (quad == 0) ? gender : (quad == 1) ? age : occupation; \
      SC = (quad < 3) ? sp[rr] : 0.0f; } }
#define WRITE_RBUF(B, G, SC) { \
    float* rb_ = rbase + (B) * RBUFSZ; \
    _Pragma("unroll") \
    for (int r = 0; r < 4; ++r) { int gi = lane + r * 64; int rw = gi / NGEN; \
        int cl = gi - rw * NGEN; rb_[rw * RSTRIDE + 3 + cl] = G[r]; } \
    if (lane < 32) { int gi = lane + 256; int rw = gi / NGEN; int cl = gi - rw * NGEN; \
        rb_[rw * RSTRIDE + 3 + cl] = G[4]; } \
    if (quad < 3) rb_[m * RSTRIDE + quad] = SC; }
#define ISSUE_GATHER(UID, MID, P) { \
    const float4* up_ = (const float4*)(user_table + (size_t)(UID) * EMB + quad * 8); \
    P.u0 = up_[0]; P.u1 = up_[1]; \
    const float4* mp_ = (const float4*)(movie_table + (size_t)(MID) * EMB + quad * 8); \
    P.m0 = mp_[0]; P.m1 = mp_[1]; \
    P.wu = wide_W[UID]; P.wm = wide_W[NUSERS + (MID)]; }

    if (niter > 0) {
        int t_c = gwave;
        int t_n = t_c + nwaves; if (t_n >= ntiles) t_n = t_c;

        int uid_c, mid_c, uid_n, mid_n, uid_n2, mid_n2;
        float gg_c[5], sc_c, gg_n[5], sc_n;
        Pref P_c, P_n;

        LOAD_IDS(t_c, uid_c, mid_c);
        LOAD_GENRES(t_c, gg_c, sc_c);
        ISSUE_GATHER(uid_c, mid_c, P_c);
        LOAD_IDS(t_n, uid_n, mid_n);
        WRITE_RBUF(0, gg_c, sc_c);
        uid_n2 = uid_n; mid_n2 = mid_n;
        int buf = 0;

        for (int i = 0; i < niter; ++i) {
            const float* rb = rbase + buf * RBUFSZ;
            const float4* sA = (const float4*)(rb + m * RSTRIDE + quad * 8);
            float4 a2a = sA[0], a2b = sA[1];

            const bool more = (i + 1 < niter);
            int t_n2 = t_n;
            if (more) {
                LOAD_GENRES(t_n, gg_n, sc_n);
                ISSUE_GATHER(uid_n, mid_n, P_n);
                t_n2 = t_n + nwaves; if (t_n2 >= ntiles) t_n2 = t_n;
                LOAD_IDS(t_n2, uid_n2, mid_n2);
            }

            const int base = t_c << 4;
            f32x8 vf;
            vf[0]=P_c.u0.x; vf[1]=P_c.u0.y; vf[2]=P_c.u0.z; vf[3]=P_c.u0.w;
            vf[4]=P_c.u1.x; vf[5]=P_c.u1.y; vf[6]=P_c.u1.z; vf[7]=P_c.u1.w;
            bf16x8 A0 = cvt8(vf);
            vf[0]=P_c.m0.x; vf[1]=P_c.m0.y; vf[2]=P_c.m0.z; vf[3]=P_c.m0.w;
            vf[4]=P_c.m1.x; vf[5]=P_c.m1.y; vf[6]=P_c.m1.z; vf[7]=P_c.m1.w;
            bf16x8 A1 = cvt8(vf);
            vf[0]=a2a.x; vf[1]=a2a.y; vf[2]=a2a.z; vf[3]=a2a.w;
            vf[4]=a2b.x; vf[5]=a2b.y; vf[6]=a2b.z; vf[7]=a2b.w;
            if (quad == 2) vf[5] = P_c.wu + P_c.wm + wb0;
            bf16x8 A2 = cvt8(vf);

            f32x4 accw = mfma16(A2, Bwf, (f32x4){0.f, 0.f, 0.f, 0.f});

            f32x4 acc[4];
            #pragma unroll
            for (int nt = 0; nt < 4; ++nt) {
                f32x4 c = {bias1[nt], bias1[nt], bias1[nt], bias1[nt]};
                c = mfma16(A0, B1f[0][nt], c);
                c = mfma16(A1, B1f[1][nt], c);
                c = mfma16(A2, B1f[2][nt], c);
                acc[nt] = c;
            }
            #pragma unroll
            for (int nt = 0; nt < 4; ++nt)
                #pragma unroll
                for (int r = 0; r < 4; ++r)
                    L1p[(quad * 4 + r) * L1STRIDE + nt * 16 + m] = fmaxf(acc[nt][r], 0.0f);

            bf16x8 AL2[2];
            #pragma unroll
            for (int kt = 0; kt < 2; ++kt) {
                const float4* s = (const float4*)(L1p + m * L1STRIDE + kt * 32 + quad * 8);
                float4 a = s[0], b = s[1];
                f32x8 t8; t8[0]=a.x; t8[1]=a.y; t8[2]=a.z; t8[3]=a.w;
                t8[4]=b.x; t8[5]=b.y; t8[6]=b.z; t8[7]=b.w;
                AL2[kt] = cvt8(t8);
            }

            f32x4 acc2[2];
            #pragma unroll
            for (int nt = 0; nt < 2; ++nt) {
                f32x4 c = {bias2[nt], bias2[nt], bias2[nt], bias2[nt]};
                c = mfma16(AL2[0], B2f[0][nt], c);
                c = mfma16(AL2[1], B2f[1][nt], c);
                acc2[nt] = c;
            }
            #pragma unroll
            for (int nt = 0; nt < 2; ++nt)
                #pragma unroll
                for (int r = 0; r < 4; ++r)
                    L2p[(quad * 4 + r) * L2STRIDE + nt * 16 + m] = fmaxf(acc2[nt][r], 0.0f);

            bf16x8 AL3;
            {
                const float4* s = (const float4*)(L2p + m * L2STRIDE + quad * 8);
                float4 a = s[0], b = s[1];
                f32x8 t8; t8[0]=a.x; t8[1]=a.y; t8[2]=a.z; t8[3]=a.w;
                t8[4]=b.x; t8[5]=b.y; t8[6]=b.z; t8[7]=b.w;
                AL3 = cvt8(t8);
            }

            f32x4 acc3 = mfma16(AL3, B3f, (f32x4){bias3, bias3, bias3, bias3});

            float t0 = fmaxf(acc3[0], 0.0f) * w4v + accw[0];
            float t1 = fmaxf(acc3[1], 0.0f) * w4v + accw[1];
            float t2 = fmaxf(acc3[2], 0.0f) * w4v + accw[2];
            float t3 = fmaxf(acc3[3], 0.0f) * w4v + accw[3];
            #pragma unroll
            for (int off = 1; off < 16; off <<= 1) {
                t0 += __shfl_xor(t0, off, 64);
                t1 += __shfl_xor(t1, off, 64);
                t2 += __shfl_xor(t2, off, 64);
                t3 += __shfl_xor(t3, off, 64);
            }
            if (m < 4) {
                float zv = t0;
                zv = (m == 1) ? t1 : zv;
                zv = (m == 2) ? t2 : zv;
                zv = (m == 3) ? t3 : zv;
                zv += b4v;
                const int orow = base + quad * 4 + m;
                if (orow < n) out[orow] = 1.0f / (1.0f + __expf(-zv));
            }

            if (more) {
                WRITE_RBUF(buf ^ 1, gg_n, sc_n);
                P_c = P_n;
                uid_c = uid_n; mid_c = mid_n;
                uid_n = uid_n2; mid_n = mid_n2;
                t_c = t_n; t_n = t_n2;
                buf ^= 1;
            }
        }
    }
#undef LOAD_IDS
#undef LOAD_GENRES
#undef WRITE_RBUF
#undef ISSUE_GATHER
}

extern "C" void kernel_launch(void* const* d_in, const int* in_sizes, int n_in,
                              void* d_out, int out_size, void* d_ws, size_t ws_size,
                              hipStream_t stream)
{
    const int*   user_ids   = (const int*)  d_in[0];
    const int*   movie_ids  = (const int*)  d_in[1];
    const float* gender     = (const float*)d_in[2];
    const float* age        = (const float*)d_in[3];
    const float* occupation = (const float*)d_in[4];
    const float* genres     = (const float*)d_in[5];
    const float* wide_W     = (const float*)d_in[6];
    const float* wide_b     = (const float*)d_in[7];
    const float* user_table = (const float*)d_in[8];
    const float* movie_table= (const float*)d_in[9];
    const float* W1         = (const float*)d_in[10];
    const float* b1         = (const float*)d_in[11];
    const float* W2         = (const float*)d_in[12];
    const float* b2         = (const float*)d_in[13];
    const float* W3         = (const float*)d_in[14];
    const float* b3         = (const float*)d_in[15];
    const float* W4         = (const float*)d_in[16];
    const float* b4         = (const float*)d_in[17];
    float*       out        = (float*)d_out;

    const int n = in_sizes[0];

    // workspace layout: utab | mtab | rest (all 256B-aligned)
    const size_t utab_bytes = ((size_t)NUSERS  * EMB * 2 + 255) & ~(size_t)255;  // 386816
    const size_t mtab_bytes = ((size_t)NMOVIES * EMB * 2 + 255) & ~(size_t)255;  // 253184
    const size_t rest_bytes = (size_t)n * RESTW * 2;
    const size_t need = utab_bytes + mtab_bytes + rest_bytes;

    if (d_ws != nullptr && ws_size >= need) {
        bf16_t* utab = (bf16_t*)d_ws;
        bf16_t* mtab = (bf16_t*)((char*)d_ws + utab_bytes);
        bf16_t* rest = (bf16_t*)((char*)d_ws + utab_bytes + mtab_bytes);

        const int prep_threads = (n > TAB4TOT) ? n : TAB4TOT;
        const int prep_blocks  = (prep_threads + 255) / 256;
        prep_all<<<prep_blocks, 256, 0, stream>>>(gender, age, occupation, genres,
                                                  user_table, movie_table,
                                                  rest, utab, mtab, n);
        wd_fwd_main<<<1024, 256, 0, stream>>>(user_ids, movie_ids, wide_W, wide_b,
                                              W1, b1, W2, b2, W3, b3, W4, b4,
                                              utab, mtab, rest, out, n);
    } else {
        wd_fwd_pipe<<<1024, 256, 0, stream>>>(user_ids, movie_ids, gender, age, occupation,
                                              genres, wide_W, wide_b, user_table, movie_table,
                                              W1, b1, W2, b2, W3, b3, W4, b4, out, n);
    }
}